// Round 9
// baseline (172.559 us; speedup 1.0000x reference)
//
#include <hip/hip_runtime.h>
#include <math.h>

// Neighborlist screening: gather -> diff -> norm -> (dummy & cutoff) mask.
// Round 9: R8 structure unchanged; single change = atom gathers are also
// non-temporal (no L1 allocate). Discriminates "per-CU L1 miss-path is the
// wall" (time drops) vs "L2 residency of atoms is what matters" (time rises).
//
// Outputs (flat float32 in d_out):
//   [0,   P)  : screened i0 as float (-1.0 if screened out)
//   [P,  2P)  : screened i1 as float
//   [2P, 3P)  : distances
//   [3P, 6P)  : diff_vectors, row-major [P][3]
#define CUTOFF_F 5.2f
#define BLOCK 256
#define PPT 8                 // pairs per thread (two chunks of 4)
#define BP (BLOCK * PPT)      // 2048 pairs per tile

typedef float f32x4 __attribute__((ext_vector_type(4)));
typedef int   i32x4 __attribute__((ext_vector_type(4)));

__global__ __launch_bounds__(BLOCK) void pack_atoms_kernel(
    const int*   __restrict__ species,   // [N]
    const float* __restrict__ coords,    // [N*3]
    f32x4*       __restrict__ atoms,     // [N] packed (x,y,z,flag)
    int N)
{
    const int n = blockIdx.x * blockDim.x + threadIdx.x;
    if (n >= N) return;
    f32x4 a;
    a.x = coords[3l*n]; a.y = coords[3l*n+1]; a.z = coords[3l*n+2];
    a.w = (species[n] == -1) ? -1.0f : 0.0f;
    atoms[n] = a;
}

__global__ __launch_bounds__(BLOCK) void nbr_screen_pipe_kernel(
    const f32x4* __restrict__ atoms,     // [N] packed (x,y,z,flag)
    const int*   __restrict__ nbr,       // [2*P]
    const float* __restrict__ shift,     // [P*3]
    float*       __restrict__ out,       // [6*P]
    int P)
{
    __shared__ f32x4 lds[6 * BLOCK];     // 1536 float4 = 24 KB (shift, then dv)
    const int tid    = threadIdx.x;
    const int nTiles = (P + BP - 1) / BP;
    const int t0     = blockIdx.x;
    if (t0 >= nTiles) return;

    // ---- prologue: load nbr indices for this block's first tile ----
    i32x4 c0A, c1A, c0B, c1B;
    {
        const long PB = (long)t0 * BP;
        if (PB + BP <= P) {
            const long baseA = PB + (long)tid * 4;
            const long baseB = baseA + (long)BLOCK * 4;
            c0A = __builtin_nontemporal_load(reinterpret_cast<const i32x4*>(nbr + baseA));
            c1A = __builtin_nontemporal_load(reinterpret_cast<const i32x4*>(nbr + (long)P + baseA));
            c0B = __builtin_nontemporal_load(reinterpret_cast<const i32x4*>(nbr + baseB));
            c1B = __builtin_nontemporal_load(reinterpret_cast<const i32x4*>(nbr + (long)P + baseB));
        }
    }

    for (int t = t0; t < nTiles; t += gridDim.x) {
        const long PB = (long)t * BP;
        if (PB + BP <= P) {
            const long baseA = PB + (long)tid * 4;
            const long baseB = baseA + (long)BLOCK * 4;

            const int ia[8] = {c0A.x, c0A.y, c0A.z, c0A.w, c0B.x, c0B.y, c0B.z, c0B.w};
            const int ib[8] = {c1A.x, c1A.y, c1A.z, c1A.w, c1B.x, c1B.y, c1B.z, c1B.w};

            // ---- issue all 16 atom gathers FIRST; NT = no L1 allocate ----
            f32x4 A[8], B[8];
            #pragma unroll
            for (int k = 0; k < 8; ++k) {
                A[k] = __builtin_nontemporal_load(atoms + ia[k]);
                B[k] = __builtin_nontemporal_load(atoms + ib[k]);
            }

            // ---- shift loads for this tile (latency hides under gathers) ----
            const f32x4* src = reinterpret_cast<const f32x4*>(shift + PB * 3);
            f32x4 sreg[6];
            #pragma unroll
            for (int q = 0; q < 6; ++q)
                sreg[q] = __builtin_nontemporal_load(src + q * BLOCK + tid);

            // ---- prefetch next tile's nbr indices (needed ~1 iter later) ----
            const int  tn   = t + gridDim.x;
            const long PBn  = (long)tn * BP;
            i32x4 n0A, n1A, n0B, n1B;
            const bool pre = (PBn + BP <= P);
            if (pre) {
                const long bA = PBn + (long)tid * 4;
                const long bB = bA + (long)BLOCK * 4;
                n0A = __builtin_nontemporal_load(reinterpret_cast<const i32x4*>(nbr + bA));
                n1A = __builtin_nontemporal_load(reinterpret_cast<const i32x4*>(nbr + (long)P + bA));
                n0B = __builtin_nontemporal_load(reinterpret_cast<const i32x4*>(nbr + bB));
                n1B = __builtin_nontemporal_load(reinterpret_cast<const i32x4*>(nbr + (long)P + bB));
            }

            // ---- stage shift into LDS ----
            #pragma unroll
            for (int q = 0; q < 6; ++q)
                lds[q * BLOCK + tid] = sreg[q];
            __syncthreads();

            const f32x4 sA0 = lds[tid*3+0], sA1 = lds[tid*3+1], sA2 = lds[tid*3+2];
            const f32x4 sB0 = lds[3*BLOCK + tid*3+0], sB1 = lds[3*BLOCK + tid*3+1],
                        sB2 = lds[3*BLOCK + tid*3+2];
            const float shf[24] = {sA0.x, sA0.y, sA0.z, sA0.w,
                                   sA1.x, sA1.y, sA1.z, sA1.w,
                                   sA2.x, sA2.y, sA2.z, sA2.w,
                                   sB0.x, sB0.y, sB0.z, sB0.w,
                                   sB1.x, sB1.y, sB1.z, sB1.w,
                                   sB2.x, sB2.y, sB2.z, sB2.w};

            float oi0[8], oi1[8], od[8], dv[24];
            #pragma unroll
            for (int k = 0; k < 8; ++k) {
                const bool valid = (A[k].w == 0.0f) & (B[k].w == 0.0f);
                // (c0 - c1) + shift, left-to-right like the reference
                const float dx = (A[k].x - B[k].x) + shf[3*k];
                const float dy = (A[k].y - B[k].y) + shf[3*k+1];
                const float dz = (A[k].z - B[k].z) + shf[3*k+2];
                // block fma contraction: bit-match numpy (x*x + y*y) + z*z
                const float d2 = __fadd_rn(__fadd_rn(__fmul_rn(dx, dx),
                                                     __fmul_rn(dy, dy)),
                                           __fmul_rn(dz, dz));
                const float dist = (d2 > 0.0f) ? sqrtf(d2) : 0.0f;
                const bool keep = valid && (dist <= CUTOFF_F);
                oi0[k] = keep ? (float)ia[k] : -1.0f;
                oi1[k] = keep ? (float)ib[k] : -1.0f;
                od[k]  = keep ? dist : 0.0f;
                dv[3*k]   = keep ? dx : 0.0f;
                dv[3*k+1] = keep ? dy : 0.0f;
                dv[3*k+2] = keep ? dz : 0.0f;
            }

            // dv into the same LDS slots each thread just read (no barrier)
            f32x4 w;
            w.x = dv[0];  w.y = dv[1];  w.z = dv[2];  w.w = dv[3];  lds[tid*3+0] = w;
            w.x = dv[4];  w.y = dv[5];  w.z = dv[6];  w.w = dv[7];  lds[tid*3+1] = w;
            w.x = dv[8];  w.y = dv[9];  w.z = dv[10]; w.w = dv[11]; lds[tid*3+2] = w;
            w.x = dv[12]; w.y = dv[13]; w.z = dv[14]; w.w = dv[15]; lds[3*BLOCK + tid*3+0] = w;
            w.x = dv[16]; w.y = dv[17]; w.z = dv[18]; w.w = dv[19]; lds[3*BLOCK + tid*3+1] = w;
            w.x = dv[20]; w.y = dv[21]; w.z = dv[22]; w.w = dv[23]; lds[3*BLOCK + tid*3+2] = w;

            // unit-stride NT stores for indices + distances (both chunks)
            f32x4 v;
            f32x4* o0 = reinterpret_cast<f32x4*>(out);
            f32x4* o1 = reinterpret_cast<f32x4*>(out + (long)P);
            f32x4* o2 = reinterpret_cast<f32x4*>(out + 2l*P);
            v.x = oi0[0]; v.y = oi0[1]; v.z = oi0[2]; v.w = oi0[3];
            __builtin_nontemporal_store(v, o0 + (baseA >> 2));
            v.x = oi0[4]; v.y = oi0[5]; v.z = oi0[6]; v.w = oi0[7];
            __builtin_nontemporal_store(v, o0 + (baseB >> 2));
            v.x = oi1[0]; v.y = oi1[1]; v.z = oi1[2]; v.w = oi1[3];
            __builtin_nontemporal_store(v, o1 + (baseA >> 2));
            v.x = oi1[4]; v.y = oi1[5]; v.z = oi1[6]; v.w = oi1[7];
            __builtin_nontemporal_store(v, o1 + (baseB >> 2));
            v.x = od[0];  v.y = od[1];  v.z = od[2];  v.w = od[3];
            __builtin_nontemporal_store(v, o2 + (baseA >> 2));
            v.x = od[4];  v.y = od[5];  v.z = od[6];  v.w = od[7];
            __builtin_nontemporal_store(v, o2 + (baseB >> 2));

            __syncthreads();

            // coop store dv region unit-stride (full-line NT stores)
            f32x4* dst = reinterpret_cast<f32x4*>(out + 3l*P + PB*3);
            #pragma unroll
            for (int q = 0; q < 6; ++q)
                __builtin_nontemporal_store(lds[q * BLOCK + tid],
                                            dst + q * BLOCK + tid);

            if (pre) { c0A = n0A; c1A = n1A; c0B = n0B; c1B = n1B; }
        } else {
            // ---- scalar tail (partial tile) ----
            for (long p = PB + tid; p < P; p += BLOCK) {
                const int a = nbr[p], b = nbr[(long)P + p];
                const f32x4 ca = atoms[a], cb = atoms[b];
                const bool valid = (ca.w == 0.0f) & (cb.w == 0.0f);
                const float dx = (ca.x - cb.x) + shift[p*3];
                const float dy = (ca.y - cb.y) + shift[p*3+1];
                const float dz = (ca.z - cb.z) + shift[p*3+2];
                const float d2 = __fadd_rn(__fadd_rn(__fmul_rn(dx, dx),
                                                     __fmul_rn(dy, dy)),
                                           __fmul_rn(dz, dz));
                const float dist = (d2 > 0.0f) ? sqrtf(d2) : 0.0f;
                const bool keep = valid && (dist <= CUTOFF_F);
                out[p]         = keep ? (float)a : -1.0f;
                out[(long)P+p] = keep ? (float)b : -1.0f;
                out[2l*P+p]    = keep ? dist : 0.0f;
                out[3l*P+p*3]   = keep ? dx : 0.0f;
                out[3l*P+p*3+1] = keep ? dy : 0.0f;
                out[3l*P+p*3+2] = keep ? dz : 0.0f;
            }
        }
    }
}

extern "C" void kernel_launch(void* const* d_in, const int* in_sizes, int n_in,
                              void* d_out, int out_size, void* d_ws, size_t ws_size,
                              hipStream_t stream) {
    const int*   species = (const int*)  d_in[0];   // (1, N) int32
    const float* coords  = (const float*)d_in[1];   // (1, N, 3) f32
    const int*   nbr     = (const int*)  d_in[2];   // (2, P) int32
    const float* shift   = (const float*)d_in[3];   // (P, 3) f32
    float* out = (float*)d_out;                     // 6*P floats

    const int N = in_sizes[0];
    const int P = in_sizes[2] / 2;

    f32x4* atoms = (f32x4*)d_ws;
    hipLaunchKernelGGL(pack_atoms_kernel, dim3((N + BLOCK - 1) / BLOCK),
                       dim3(BLOCK), 0, stream, species, coords, atoms, N);

    const int nTiles = (P + BP - 1) / BP;
    int grid = 1024;
    if (grid > nTiles) grid = nTiles;
    hipLaunchKernelGGL(nbr_screen_pipe_kernel, dim3(grid), dim3(BLOCK), 0,
                       stream, atoms, nbr, shift, out, P);
}

// Round 10
// 93.095 us; speedup vs baseline: 1.8536x; 1.8536x over previous
//
#include <hip/hip_runtime.h>
#include <math.h>

// Neighborlist screening: gather -> diff -> norm -> (dummy & cutoff) mask.
// Round 10: REVERT to R8 (best: 93.1 us timed). R9's NT-on-gathers proved the
// gathers are L2-served (NT eviction -> FETCH 69->155MB, 175 us). R6-R9 showed
// time invariant (91-96 us) across occupancy 60->23%, MLP 8->16, pipelining:
// saturated L2 random-service path at the lane-request floor (30.4M requests,
// all 16B/lane max width). This config is the measured ceiling.
//
// Outputs (flat float32 in d_out):
//   [0,   P)  : screened i0 as float (-1.0 if screened out)
//   [P,  2P)  : screened i1 as float
//   [2P, 3P)  : distances
//   [3P, 6P)  : diff_vectors, row-major [P][3]
#define CUTOFF_F 5.2f
#define BLOCK 256
#define PPT 8                 // pairs per thread (two chunks of 4)
#define BP (BLOCK * PPT)      // 2048 pairs per tile

typedef float f32x4 __attribute__((ext_vector_type(4)));
typedef int   i32x4 __attribute__((ext_vector_type(4)));

__global__ __launch_bounds__(BLOCK) void pack_atoms_kernel(
    const int*   __restrict__ species,   // [N]
    const float* __restrict__ coords,    // [N*3]
    f32x4*       __restrict__ atoms,     // [N] packed (x,y,z,flag)
    int N)
{
    const int n = blockIdx.x * blockDim.x + threadIdx.x;
    if (n >= N) return;
    f32x4 a;
    a.x = coords[3l*n]; a.y = coords[3l*n+1]; a.z = coords[3l*n+2];
    a.w = (species[n] == -1) ? -1.0f : 0.0f;
    atoms[n] = a;
}

__global__ __launch_bounds__(BLOCK) void nbr_screen_pipe_kernel(
    const f32x4* __restrict__ atoms,     // [N] packed (x,y,z,flag)
    const int*   __restrict__ nbr,       // [2*P]
    const float* __restrict__ shift,     // [P*3]
    float*       __restrict__ out,       // [6*P]
    int P)
{
    __shared__ f32x4 lds[6 * BLOCK];     // 1536 float4 = 24 KB (shift, then dv)
    const int tid    = threadIdx.x;
    const int nTiles = (P + BP - 1) / BP;
    const int t0     = blockIdx.x;
    if (t0 >= nTiles) return;

    // ---- prologue: load nbr indices for this block's first tile ----
    i32x4 c0A, c1A, c0B, c1B;
    {
        const long PB = (long)t0 * BP;
        if (PB + BP <= P) {
            const long baseA = PB + (long)tid * 4;
            const long baseB = baseA + (long)BLOCK * 4;
            c0A = __builtin_nontemporal_load(reinterpret_cast<const i32x4*>(nbr + baseA));
            c1A = __builtin_nontemporal_load(reinterpret_cast<const i32x4*>(nbr + (long)P + baseA));
            c0B = __builtin_nontemporal_load(reinterpret_cast<const i32x4*>(nbr + baseB));
            c1B = __builtin_nontemporal_load(reinterpret_cast<const i32x4*>(nbr + (long)P + baseB));
        }
    }

    for (int t = t0; t < nTiles; t += gridDim.x) {
        const long PB = (long)t * BP;
        if (PB + BP <= P) {
            const long baseA = PB + (long)tid * 4;
            const long baseB = baseA + (long)BLOCK * 4;

            const int ia[8] = {c0A.x, c0A.y, c0A.z, c0A.w, c0B.x, c0B.y, c0B.z, c0B.w};
            const int ib[8] = {c1A.x, c1A.y, c1A.z, c1A.w, c1B.x, c1B.y, c1B.z, c1B.w};

            // ---- issue all 16 atom gathers FIRST (addresses already resident)
            //      REGULAR loads: atoms must stay L2-resident (R9 proof)
            f32x4 A[8], B[8];
            #pragma unroll
            for (int k = 0; k < 8; ++k) { A[k] = atoms[ia[k]]; B[k] = atoms[ib[k]]; }

            // ---- shift loads for this tile (latency hides under gathers) ----
            const f32x4* src = reinterpret_cast<const f32x4*>(shift + PB * 3);
            f32x4 sreg[6];
            #pragma unroll
            for (int q = 0; q < 6; ++q)
                sreg[q] = __builtin_nontemporal_load(src + q * BLOCK + tid);

            // ---- prefetch next tile's nbr indices (needed ~1 iter later) ----
            const int  tn   = t + gridDim.x;
            const long PBn  = (long)tn * BP;
            i32x4 n0A, n1A, n0B, n1B;
            const bool pre = (PBn + BP <= P);
            if (pre) {
                const long bA = PBn + (long)tid * 4;
                const long bB = bA + (long)BLOCK * 4;
                n0A = __builtin_nontemporal_load(reinterpret_cast<const i32x4*>(nbr + bA));
                n1A = __builtin_nontemporal_load(reinterpret_cast<const i32x4*>(nbr + (long)P + bA));
                n0B = __builtin_nontemporal_load(reinterpret_cast<const i32x4*>(nbr + bB));
                n1B = __builtin_nontemporal_load(reinterpret_cast<const i32x4*>(nbr + (long)P + bB));
            }

            // ---- stage shift into LDS ----
            #pragma unroll
            for (int q = 0; q < 6; ++q)
                lds[q * BLOCK + tid] = sreg[q];
            __syncthreads();

            const f32x4 sA0 = lds[tid*3+0], sA1 = lds[tid*3+1], sA2 = lds[tid*3+2];
            const f32x4 sB0 = lds[3*BLOCK + tid*3+0], sB1 = lds[3*BLOCK + tid*3+1],
                        sB2 = lds[3*BLOCK + tid*3+2];
            const float shf[24] = {sA0.x, sA0.y, sA0.z, sA0.w,
                                   sA1.x, sA1.y, sA1.z, sA1.w,
                                   sA2.x, sA2.y, sA2.z, sA2.w,
                                   sB0.x, sB0.y, sB0.z, sB0.w,
                                   sB1.x, sB1.y, sB1.z, sB1.w,
                                   sB2.x, sB2.y, sB2.z, sB2.w};

            float oi0[8], oi1[8], od[8], dv[24];
            #pragma unroll
            for (int k = 0; k < 8; ++k) {
                const bool valid = (A[k].w == 0.0f) & (B[k].w == 0.0f);
                // (c0 - c1) + shift, left-to-right like the reference
                const float dx = (A[k].x - B[k].x) + shf[3*k];
                const float dy = (A[k].y - B[k].y) + shf[3*k+1];
                const float dz = (A[k].z - B[k].z) + shf[3*k+2];
                // block fma contraction: bit-match numpy (x*x + y*y) + z*z
                const float d2 = __fadd_rn(__fadd_rn(__fmul_rn(dx, dx),
                                                     __fmul_rn(dy, dy)),
                                           __fmul_rn(dz, dz));
                const float dist = (d2 > 0.0f) ? sqrtf(d2) : 0.0f;
                const bool keep = valid && (dist <= CUTOFF_F);
                oi0[k] = keep ? (float)ia[k] : -1.0f;
                oi1[k] = keep ? (float)ib[k] : -1.0f;
                od[k]  = keep ? dist : 0.0f;
                dv[3*k]   = keep ? dx : 0.0f;
                dv[3*k+1] = keep ? dy : 0.0f;
                dv[3*k+2] = keep ? dz : 0.0f;
            }

            // dv into the same LDS slots each thread just read (no barrier)
            f32x4 w;
            w.x = dv[0];  w.y = dv[1];  w.z = dv[2];  w.w = dv[3];  lds[tid*3+0] = w;
            w.x = dv[4];  w.y = dv[5];  w.z = dv[6];  w.w = dv[7];  lds[tid*3+1] = w;
            w.x = dv[8];  w.y = dv[9];  w.z = dv[10]; w.w = dv[11]; lds[tid*3+2] = w;
            w.x = dv[12]; w.y = dv[13]; w.z = dv[14]; w.w = dv[15]; lds[3*BLOCK + tid*3+0] = w;
            w.x = dv[16]; w.y = dv[17]; w.z = dv[18]; w.w = dv[19]; lds[3*BLOCK + tid*3+1] = w;
            w.x = dv[20]; w.y = dv[21]; w.z = dv[22]; w.w = dv[23]; lds[3*BLOCK + tid*3+2] = w;

            // unit-stride NT stores for indices + distances (both chunks)
            f32x4 v;
            f32x4* o0 = reinterpret_cast<f32x4*>(out);
            f32x4* o1 = reinterpret_cast<f32x4*>(out + (long)P);
            f32x4* o2 = reinterpret_cast<f32x4*>(out + 2l*P);
            v.x = oi0[0]; v.y = oi0[1]; v.z = oi0[2]; v.w = oi0[3];
            __builtin_nontemporal_store(v, o0 + (baseA >> 2));
            v.x = oi0[4]; v.y = oi0[5]; v.z = oi0[6]; v.w = oi0[7];
            __builtin_nontemporal_store(v, o0 + (baseB >> 2));
            v.x = oi1[0]; v.y = oi1[1]; v.z = oi1[2]; v.w = oi1[3];
            __builtin_nontemporal_store(v, o1 + (baseA >> 2));
            v.x = oi1[4]; v.y = oi1[5]; v.z = oi1[6]; v.w = oi1[7];
            __builtin_nontemporal_store(v, o1 + (baseB >> 2));
            v.x = od[0];  v.y = od[1];  v.z = od[2];  v.w = od[3];
            __builtin_nontemporal_store(v, o2 + (baseA >> 2));
            v.x = od[4];  v.y = od[5];  v.z = od[6];  v.w = od[7];
            __builtin_nontemporal_store(v, o2 + (baseB >> 2));

            __syncthreads();

            // coop store dv region unit-stride (full-line NT stores)
            f32x4* dst = reinterpret_cast<f32x4*>(out + 3l*P + PB*3);
            #pragma unroll
            for (int q = 0; q < 6; ++q)
                __builtin_nontemporal_store(lds[q * BLOCK + tid],
                                            dst + q * BLOCK + tid);

            if (pre) { c0A = n0A; c1A = n1A; c0B = n0B; c1B = n1B; }
        } else {
            // ---- scalar tail (partial tile) ----
            for (long p = PB + tid; p < P; p += BLOCK) {
                const int a = nbr[p], b = nbr[(long)P + p];
                const f32x4 ca = atoms[a], cb = atoms[b];
                const bool valid = (ca.w == 0.0f) & (cb.w == 0.0f);
                const float dx = (ca.x - cb.x) + shift[p*3];
                const float dy = (ca.y - cb.y) + shift[p*3+1];
                const float dz = (ca.z - cb.z) + shift[p*3+2];
                const float d2 = __fadd_rn(__fadd_rn(__fmul_rn(dx, dx),
                                                     __fmul_rn(dy, dy)),
                                           __fmul_rn(dz, dz));
                const float dist = (d2 > 0.0f) ? sqrtf(d2) : 0.0f;
                const bool keep = valid && (dist <= CUTOFF_F);
                out[p]         = keep ? (float)a : -1.0f;
                out[(long)P+p] = keep ? (float)b : -1.0f;
                out[2l*P+p]    = keep ? dist : 0.0f;
                out[3l*P+p*3]   = keep ? dx : 0.0f;
                out[3l*P+p*3+1] = keep ? dy : 0.0f;
                out[3l*P+p*3+2] = keep ? dz : 0.0f;
            }
        }
    }
}

extern "C" void kernel_launch(void* const* d_in, const int* in_sizes, int n_in,
                              void* d_out, int out_size, void* d_ws, size_t ws_size,
                              hipStream_t stream) {
    const int*   species = (const int*)  d_in[0];   // (1, N) int32
    const float* coords  = (const float*)d_in[1];   // (1, N, 3) f32
    const int*   nbr     = (const int*)  d_in[2];   // (2, P) int32
    const float* shift   = (const float*)d_in[3];   // (P, 3) f32
    float* out = (float*)d_out;                     // 6*P floats

    const int N = in_sizes[0];
    const int P = in_sizes[2] / 2;

    f32x4* atoms = (f32x4*)d_ws;
    hipLaunchKernelGGL(pack_atoms_kernel, dim3((N + BLOCK - 1) / BLOCK),
                       dim3(BLOCK), 0, stream, species, coords, atoms, N);

    const int nTiles = (P + BP - 1) / BP;
    int grid = 1024;
    if (grid > nTiles) grid = nTiles;
    hipLaunchKernelGGL(nbr_screen_pipe_kernel, dim3(grid), dim3(BLOCK), 0,
                       stream, atoms, nbr, shift, out, P);
}